// Round 1
// baseline (586.263 us; speedup 1.0000x reference)
//
#include <hip/hip_runtime.h>
#include <hip/hip_bf16.h>
#include <stdint.h>

typedef __bf16 bf16x8 __attribute__((ext_vector_type(8)));
typedef float  f32x4  __attribute__((ext_vector_type(4)));

#define NATOMS  32768
#define NEXP    4
#define MAXROWS (NATOMS + NEXP*128)   // 33280 (max padded rows)
#define MBLKS   (MAXROWS/128)         // 260

// ---------------- ws layout (bytes) ----------------
#define WS_HDR   0u
#define WS_PERM  1024u                        // int[33280] -> ends 134144
#define WS_W1T   134144u                      // [4][512][1024] bf16 = 4194304
#define WS_W2T   (WS_W1T + 4194304u)          // [4][128][512]  bf16 = 524288
#define WS_W3T   (WS_W2T + 524288u)           // [4][512][128]  bf16 = 524288
#define WS_W4T   (WS_W3T + 524288u)           // [4][1024][512] bf16 = 4194304
#define WS_H     (WS_W4T + 4194304u)          // [33280][512] bf16 = 34078720
#define WS_Z     (WS_H + 34078720u)           // [33280][128] bf16 = 8519680
#define WS_D     WS_H                         // alias: h dead after L2

__device__ __forceinline__ unsigned short f2bf(float f){
  union { float f; uint32_t u; } v; v.f = f;
  uint32_t r = v.u + 0x7fffu + ((v.u >> 16) & 1u);   // RNE
  return (unsigned short)(r >> 16);
}
__device__ __forceinline__ uint32_t pk2(float a, float b){
  return (uint32_t)f2bf(a) | ((uint32_t)f2bf(b) << 16);
}

// ---------------- routing: stable bucket-by-expert, 128-padded ----------------
__global__ __launch_bounds__(1024) void route_kernel(const int* __restrict__ sym,
                                                     int* __restrict__ hdr,
                                                     int* __restrict__ perm){
  __shared__ unsigned wsumA[16], wsumB[16];
  __shared__ unsigned wexclA[16], wexclB[16];
  __shared__ int pof[NEXP+1];
  __shared__ int tot[NEXP];
  const int t = threadIdx.x;
  const int lane = t & 63, w = t >> 6;
  int c0=0,c1=0,c2=0,c3=0;
  const int base = t*32;                       // 1024*32 == 32768 exactly
  for (int i=0;i<32;++i){
    int s = sym[base+i];
    c0 += (s==0); c1 += (s==1); c2 += (s==2); c3 += (s==3);
  }
  unsigned pA = (unsigned)c0 | ((unsigned)c1<<16);
  unsigned pB = (unsigned)c2 | ((unsigned)c3<<16);
  unsigned iA = pA, iB = pB;
  #pragma unroll
  for (int d=1; d<64; d<<=1){
    unsigned uA = __shfl_up(iA, d, 64);
    unsigned uB = __shfl_up(iB, d, 64);
    if (lane >= d){ iA += uA; iB += uB; }
  }
  unsigned exA = iA - pA, exB = iB - pB;       // in-wave exclusive (packed)
  if (lane == 63){ wsumA[w] = iA; wsumB[w] = iB; }
  __syncthreads();
  if (w == 0 && lane < 16){
    unsigned vA = wsumA[lane], vB = wsumB[lane];
    unsigned jA = vA, jB = vB;
    #pragma unroll
    for (int d=1; d<16; d<<=1){
      unsigned uA = __shfl_up(jA, d, 64);
      unsigned uB = __shfl_up(jB, d, 64);
      if (lane >= d){ jA += uA; jB += uB; }
    }
    wexclA[lane] = jA - vA; wexclB[lane] = jB - vB;
    if (lane == 15){
      tot[0] = (int)(jA & 0xFFFFu); tot[1] = (int)(jA >> 16);
      tot[2] = (int)(jB & 0xFFFFu); tot[3] = (int)(jB >> 16);
      int o = 0; pof[0] = 0;
      for (int e=0;e<NEXP;++e){ o += (tot[e]+127)&~127; pof[e+1]=o; }
      for (int e=0;e<=NEXP;++e) hdr[e]=pof[e];
    }
  }
  __syncthreads();
  const unsigned bA = wexclA[w] + exA, bB = wexclB[w] + exB;
  int p0 = pof[0] + (int)(bA & 0xFFFFu);
  int p1 = pof[1] + (int)(bA >> 16);
  int p2 = pof[2] + (int)(bB & 0xFFFFu);
  int p3 = pof[3] + (int)(bB >> 16);
  const int totpad = pof[NEXP];
  for (int i=t; i<totpad; i+=1024) perm[i] = -1;   // pad rows
  __syncthreads();
  for (int i=0;i<32;++i){
    int a = base+i; int s = sym[a];
    if      (s==0) perm[p0++] = a;
    else if (s==1) perm[p1++] = a;
    else if (s==2) perm[p2++] = a;
    else           perm[p3++] = a;
  }
}

// ---------------- weight convert fp32 [E][K][NO] -> bf16 [E][NO][K] ----------------
template<int K, int NO>
__global__ __launch_bounds__(256) void wconvert(const float* __restrict__ W,
                                                unsigned short* __restrict__ Bt){
  __shared__ unsigned short tile[64][65];
  const int e  = blockIdx.z;
  const int k0 = blockIdx.y * 64;
  const int n0 = blockIdx.x * 64;
  const int t  = threadIdx.x;
  const int c  = t & 63;
  const float* Wb = W + ((size_t)e*K + k0)*NO + n0;
  #pragma unroll
  for (int i=0;i<16;++i){
    int r = (t>>6) + i*4;
    tile[r][c] = f2bf(Wb[(size_t)r*NO + c]);
  }
  __syncthreads();
  unsigned short* Bb = Bt + ((size_t)e*NO + n0)*K + k0;
  #pragma unroll
  for (int i=0;i<16;++i){
    int r = (t>>6) + i*4;
    Bb[(size_t)r*K + c] = tile[c][r];
  }
}

// ---------------- 128x128 tile MFMA GEMM (BK=64, 4 waves 2x2) ----------------
// A: bf16 [Mpad][K] (or gather fp32 rows of Af via perm when GATHER)
// Bt: bf16 [E][NO][K]; bias fp32 [E][NO]
// out: bf16 [Mpad][NO] (Cb) or scatter fp32 rows to Cf [NATOMS][NO] when FINAL
template<int K, int NO, bool RELU, bool GATHER, bool FINAL>
__global__ __launch_bounds__(256) void gemm_k(
    const unsigned short* __restrict__ A,
    const float* __restrict__ Af,
    const unsigned short* __restrict__ Bt,
    const float* __restrict__ bias,
    unsigned short* __restrict__ Cb,
    float* __restrict__ Cf,
    const int* __restrict__ hdr,
    const int* __restrict__ perm)
{
  __shared__ __align__(16) unsigned short As[128*64];
  __shared__ __align__(16) unsigned short Bs[128*64];
  __shared__ int sperm[128];

  const int row0 = blockIdx.x * 128;
  if (row0 >= hdr[NEXP]) return;          // beyond padded total
  int e = 0;
  if (row0 >= hdr[1]) e = 1;
  if (row0 >= hdr[2]) e = 2;
  if (row0 >= hdr[3]) e = 3;
  const int n0 = blockIdx.y * 128;
  const unsigned short* Bte = Bt + ((size_t)e*NO + n0)*K;

  const int t = threadIdx.x;
  if (GATHER || FINAL){ if (t < 128) sperm[t] = perm[row0 + t]; }
  __syncthreads();

  const int lane = t & 63;
  const int wid  = t >> 6;
  const int wr   = (wid >> 1) * 64;   // wave row offset in tile
  const int wc   = (wid & 1) * 64;    // wave col offset in tile
  const int lr   = lane & 15;
  const int sgrp = lane >> 4;         // 0..3 -> k-slot group

  f32x4 acc[4][4];
  const f32x4 z4 = {0.f,0.f,0.f,0.f};
  #pragma unroll
  for (int mi=0;mi<4;++mi)
    #pragma unroll
    for (int ni=0;ni<4;++ni) acc[mi][ni] = z4;

  #pragma unroll 1
  for (int kt = 0; kt < K/64; ++kt){
    uint4 av[4], bv[4];
    #pragma unroll
    for (int j=0;j<4;++j){
      int cch = t + 256*j;             // 16B chunk id, 1024 chunks per tile
      int rA  = cch >> 3;              // row (8 chunks of 8 bf16 per 64-wide row)
      int k8  = (cch & 7) * 8;
      if constexpr (GATHER){
        int atom = sperm[rA];
        if (atom >= 0){
          const float* src = Af + (size_t)atom*K + kt*64 + k8;
          float4 f0 = *(const float4*)(src);
          float4 f1 = *(const float4*)(src + 4);
          av[j].x = pk2(f0.x,f0.y); av[j].y = pk2(f0.z,f0.w);
          av[j].z = pk2(f1.x,f1.y); av[j].w = pk2(f1.z,f1.w);
        } else {
          av[j] = make_uint4(0u,0u,0u,0u);
        }
      } else {
        av[j] = *(const uint4*)&A[(size_t)(row0+rA)*K + kt*64 + k8];
      }
      bv[j] = *(const uint4*)&Bte[(size_t)rA*K + kt*64 + k8];
    }
    __syncthreads();                   // previous iter's compute done with LDS
    #pragma unroll
    for (int j=0;j<4;++j){
      int cch = t + 256*j;
      int r = cch >> 3;
      int slot = (cch & 7) ^ (r & 7);  // XOR swizzle of 16B slots (bank-conflict fix)
      *(uint4*)&As[r*64 + slot*8] = av[j];
      *(uint4*)&Bs[r*64 + slot*8] = bv[j];
    }
    __syncthreads();
    #pragma unroll
    for (int kk=0;kk<2;++kk){
      bf16x8 af[4], bfr[4];
      const int s = kk*4 + sgrp;
      #pragma unroll
      for (int mi=0;mi<4;++mi){
        int R = wr + mi*16 + lr;
        af[mi] = *(const bf16x8*)&As[R*64 + ((s ^ (R & 7)) << 3)];
      }
      #pragma unroll
      for (int ni=0;ni<4;++ni){
        int Cc = wc + ni*16 + lr;
        bfr[ni] = *(const bf16x8*)&Bs[Cc*64 + ((s ^ (Cc & 7)) << 3)];
      }
      #pragma unroll
      for (int mi=0;mi<4;++mi)
        #pragma unroll
        for (int ni=0;ni<4;++ni)
          acc[mi][ni] = __builtin_amdgcn_mfma_f32_16x16x32_bf16(af[mi], bfr[ni], acc[mi][ni], 0, 0, 0);
    }
  }

  // epilogue: D row=(lane>>4)*4+q, col=lane&15 within each 16x16 fragment
  const int rsub = sgrp * 4;
  #pragma unroll
  for (int ni=0;ni<4;++ni){
    const int colg = n0 + wc + ni*16 + lr;
    const float bv_ = bias[(size_t)e*NO + colg];
    #pragma unroll
    for (int mi=0;mi<4;++mi){
      const int rloc = wr + mi*16 + rsub;
      #pragma unroll
      for (int q=0;q<4;++q){
        float v = acc[mi][ni][q] + bv_;
        if (RELU) v = fmaxf(v, 0.f);
        if constexpr (FINAL){
          int atom = sperm[rloc + q];
          if (atom >= 0) Cf[(size_t)atom*NO + colg] = v;
        } else {
          Cb[(size_t)(row0 + rloc + q)*NO + colg] = f2bf(v);
        }
      }
    }
  }
}

extern "C" void kernel_launch(void* const* d_in, const int* in_sizes, int n_in,
                              void* d_out, int out_size, void* d_ws, size_t ws_size,
                              hipStream_t stream) {
  const float* X   = (const float*)d_in[0];
  const int*   sym = (const int*)  d_in[1];
  const float* We1 = (const float*)d_in[2];
  const float* be1 = (const float*)d_in[3];
  const float* We2 = (const float*)d_in[4];
  const float* be2 = (const float*)d_in[5];
  const float* Wd1 = (const float*)d_in[6];
  const float* bd1 = (const float*)d_in[7];
  const float* Wd2 = (const float*)d_in[8];
  const float* bd2 = (const float*)d_in[9];
  float* out = (float*)d_out;

  char* ws = (char*)d_ws;
  int* hdr  = (int*)(ws + WS_HDR);
  int* perm = (int*)(ws + WS_PERM);
  unsigned short* W1t = (unsigned short*)(ws + WS_W1T);
  unsigned short* W2t = (unsigned short*)(ws + WS_W2T);
  unsigned short* W3t = (unsigned short*)(ws + WS_W3T);
  unsigned short* W4t = (unsigned short*)(ws + WS_W4T);
  unsigned short* H   = (unsigned short*)(ws + WS_H);
  unsigned short* Z   = (unsigned short*)(ws + WS_Z);
  unsigned short* Dd  = (unsigned short*)(ws + WS_D);   // aliases H (H dead after L2)

  dim3 b256(256);
  route_kernel<<<1, 1024, 0, stream>>>(sym, hdr, perm);
  wconvert<1024, 512><<<dim3( 512/64, 1024/64, NEXP), b256, 0, stream>>>(We1, W1t);
  wconvert< 512, 128><<<dim3( 128/64,  512/64, NEXP), b256, 0, stream>>>(We2, W2t);
  wconvert< 128, 512><<<dim3( 512/64,  128/64, NEXP), b256, 0, stream>>>(Wd1, W3t);
  wconvert< 512,1024><<<dim3(1024/64,  512/64, NEXP), b256, 0, stream>>>(Wd2, W4t);

  // L1: relu(X @ We1 + be1), gather fp32 X rows via perm -> H (bf16)
  gemm_k<1024, 512, true,  true,  false><<<dim3(MBLKS, 4), b256, 0, stream>>>(
      nullptr, X, W1t, be1, H, nullptr, hdr, perm);
  // L2: relu(H @ We2 + be2) -> Z
  gemm_k< 512, 128, true,  false, false><<<dim3(MBLKS, 1), b256, 0, stream>>>(
      H, nullptr, W2t, be2, Z, nullptr, hdr, perm);
  // L3: relu(Z @ Wd1 + bd1) -> Dd
  gemm_k< 128, 512, true,  false, false><<<dim3(MBLKS, 4), b256, 0, stream>>>(
      Z, nullptr, W3t, bd1, Dd, nullptr, hdr, perm);
  // L4: Dd @ Wd2 + bd2, scatter fp32 rows to out via perm
  gemm_k< 512,1024, false, false, true ><<<dim3(MBLKS, 8), b256, 0, stream>>>(
      Dd, nullptr, W4t, bd2, nullptr, out, hdr, perm);
}

// Round 2
// 570.264 us; speedup vs baseline: 1.0281x; 1.0281x over previous
//
#include <hip/hip_runtime.h>
#include <hip/hip_bf16.h>
#include <stdint.h>

typedef __bf16 bf16x8 __attribute__((ext_vector_type(8)));
typedef float  f32x4  __attribute__((ext_vector_type(4)));

#define NATOMS  32768
#define NEXP    4
#define MAXROWS (NATOMS + NEXP*128)   // 33280 (max padded rows)
#define MBLKS   (MAXROWS/128)         // 260

// ---------------- ws layout (bytes) ----------------
#define WS_HDR   0u
#define WS_PERM  1024u                        // int[33280] -> ends 134144
#define WS_W1T   134144u                      // [4][512][1024] bf16 = 4194304
#define WS_W2T   (WS_W1T + 4194304u)          // [4][128][512]  bf16 = 524288
#define WS_W3T   (WS_W2T + 524288u)           // [4][512][128]  bf16 = 524288
#define WS_W4T   (WS_W3T + 524288u)           // [4][1024][512] bf16 = 4194304
#define WS_H     (WS_W4T + 4194304u)          // [33280][512] bf16 = 34078720
#define WS_Z     (WS_H + 34078720u)           // [33280][128] bf16 = 8519680
#define WS_D     WS_H                         // alias: h dead after L2

__device__ __forceinline__ unsigned short f2bf(float f){
  union { float f; uint32_t u; } v; v.f = f;
  uint32_t r = v.u + 0x7fffu + ((v.u >> 16) & 1u);   // RNE
  return (unsigned short)(r >> 16);
}
__device__ __forceinline__ uint32_t pk2(float a, float b){
  return (uint32_t)f2bf(a) | ((uint32_t)f2bf(b) << 16);
}

// ---------------- routing: stable bucket-by-expert, 128-padded ----------------
__global__ __launch_bounds__(1024) void route_kernel(const int* __restrict__ sym,
                                                     int* __restrict__ hdr,
                                                     int* __restrict__ perm){
  __shared__ unsigned wsumA[16], wsumB[16];
  __shared__ unsigned wexclA[16], wexclB[16];
  __shared__ int pof[NEXP+1];
  __shared__ int tot[NEXP];
  const int t = threadIdx.x;
  const int lane = t & 63, w = t >> 6;
  int c0=0,c1=0,c2=0,c3=0;
  const int base = t*32;                       // 1024*32 == 32768 exactly
  for (int i=0;i<32;++i){
    int s = sym[base+i];
    c0 += (s==0); c1 += (s==1); c2 += (s==2); c3 += (s==3);
  }
  unsigned pA = (unsigned)c0 | ((unsigned)c1<<16);
  unsigned pB = (unsigned)c2 | ((unsigned)c3<<16);
  unsigned iA = pA, iB = pB;
  #pragma unroll
  for (int d=1; d<64; d<<=1){
    unsigned uA = __shfl_up(iA, d, 64);
    unsigned uB = __shfl_up(iB, d, 64);
    if (lane >= d){ iA += uA; iB += uB; }
  }
  unsigned exA = iA - pA, exB = iB - pB;       // in-wave exclusive (packed)
  if (lane == 63){ wsumA[w] = iA; wsumB[w] = iB; }
  __syncthreads();
  if (w == 0 && lane < 16){
    unsigned vA = wsumA[lane], vB = wsumB[lane];
    unsigned jA = vA, jB = vB;
    #pragma unroll
    for (int d=1; d<16; d<<=1){
      unsigned uA = __shfl_up(jA, d, 64);
      unsigned uB = __shfl_up(jB, d, 64);
      if (lane >= d){ jA += uA; jB += uB; }
    }
    wexclA[lane] = jA - vA; wexclB[lane] = jB - vB;
    if (lane == 15){
      tot[0] = (int)(jA & 0xFFFFu); tot[1] = (int)(jA >> 16);
      tot[2] = (int)(jB & 0xFFFFu); tot[3] = (int)(jB >> 16);
      int o = 0; pof[0] = 0;
      for (int e=0;e<NEXP;++e){ o += (tot[e]+127)&~127; pof[e+1]=o; }
      for (int e=0;e<=NEXP;++e) hdr[e]=pof[e];
    }
  }
  __syncthreads();
  const unsigned bA = wexclA[w] + exA, bB = wexclB[w] + exB;
  int p0 = pof[0] + (int)(bA & 0xFFFFu);
  int p1 = pof[1] + (int)(bA >> 16);
  int p2 = pof[2] + (int)(bB & 0xFFFFu);
  int p3 = pof[3] + (int)(bB >> 16);
  const int totpad = pof[NEXP];
  for (int i=t; i<totpad; i+=1024) perm[i] = -1;   // pad rows
  __syncthreads();
  for (int i=0;i<32;++i){
    int a = base+i; int s = sym[a];
    if      (s==0) perm[p0++] = a;
    else if (s==1) perm[p1++] = a;
    else if (s==2) perm[p2++] = a;
    else           perm[p3++] = a;
  }
}

// ---------------- weight convert fp32 [E][K][NO] -> bf16 [E][NO][K] ----------------
template<int K, int NO>
__global__ __launch_bounds__(256) void wconvert(const float* __restrict__ W,
                                                unsigned short* __restrict__ Bt){
  __shared__ unsigned short tile[64][65];
  const int e  = blockIdx.z;
  const int k0 = blockIdx.y * 64;
  const int n0 = blockIdx.x * 64;
  const int t  = threadIdx.x;
  const int c  = t & 63;
  const float* Wb = W + ((size_t)e*K + k0)*NO + n0;
  #pragma unroll
  for (int i=0;i<16;++i){
    int r = (t>>6) + i*4;
    tile[r][c] = f2bf(Wb[(size_t)r*NO + c]);
  }
  __syncthreads();
  unsigned short* Bb = Bt + ((size_t)e*NO + n0)*K + k0;
  #pragma unroll
  for (int i=0;i<16;++i){
    int r = (t>>6) + i*4;
    Bb[(size_t)r*K + c] = tile[c][r];
  }
}

// ---------------- 128x128 tile MFMA GEMM (BK=64, 4 waves 2x2) ----------------
// grid: (NO/128, MBLKS) -- n-tiles INNER so same-row blocks are dispatch-adjacent
// A: bf16 [Mpad][K] (or gather fp32 rows of Af via perm when GATHER)
// Bt: bf16 [E][NO][K]; bias fp32 [E][NO]
// out: bf16 [Mpad][NO] (Cb) or scatter fp32 rows to Cf [NATOMS][NO] when FINAL
// Epilogue stages the 128x128 tile in LDS and writes full rows (no partial
// 128B-line writes -> no write-allocate RMW traffic).
template<int K, int NO, bool RELU, bool GATHER, bool FINAL>
__global__ __launch_bounds__(256) void gemm_k(
    const unsigned short* __restrict__ A,
    const float* __restrict__ Af,
    const unsigned short* __restrict__ Bt,
    const float* __restrict__ bias,
    unsigned short* __restrict__ Cb,
    float* __restrict__ Cf,
    const int* __restrict__ hdr,
    const int* __restrict__ perm)
{
  __shared__ __align__(16) unsigned short smem[2*128*64];  // As | Bs (32 KB)
  __shared__ int sperm[128];
  unsigned short* As = smem;
  unsigned short* Bs = smem + 128*64;

  const int row0 = blockIdx.y * 128;
  if (row0 >= hdr[NEXP]) return;          // beyond padded total
  int e = 0;
  if (row0 >= hdr[1]) e = 1;
  if (row0 >= hdr[2]) e = 2;
  if (row0 >= hdr[3]) e = 3;
  const int n0 = blockIdx.x * 128;
  const unsigned short* Bte = Bt + ((size_t)e*NO + n0)*K;

  const int t = threadIdx.x;
  if (GATHER || FINAL){ if (t < 128) sperm[t] = perm[row0 + t]; }
  __syncthreads();

  const int lane = t & 63;
  const int wid  = t >> 6;
  const int wr   = (wid >> 1) * 64;   // wave row offset in tile
  const int wc   = (wid & 1) * 64;    // wave col offset in tile
  const int lr   = lane & 15;
  const int sgrp = lane >> 4;         // 0..3 -> k-slot group

  f32x4 acc[4][4];
  const f32x4 z4 = {0.f,0.f,0.f,0.f};
  #pragma unroll
  for (int mi=0;mi<4;++mi)
    #pragma unroll
    for (int ni=0;ni<4;++ni) acc[mi][ni] = z4;

  #pragma unroll 1
  for (int kt = 0; kt < K/64; ++kt){
    uint4 av[4], bv[4];
    #pragma unroll
    for (int j=0;j<4;++j){
      int cch = t + 256*j;             // 16B chunk id, 1024 chunks per tile
      int rA  = cch >> 3;              // row (8 chunks of 8 bf16 per 64-wide row)
      int k8  = (cch & 7) * 8;
      if constexpr (GATHER){
        int atom = sperm[rA];
        if (atom >= 0){
          const float* src = Af + (size_t)atom*K + kt*64 + k8;
          float4 f0 = *(const float4*)(src);
          float4 f1 = *(const float4*)(src + 4);
          av[j].x = pk2(f0.x,f0.y); av[j].y = pk2(f0.z,f0.w);
          av[j].z = pk2(f1.x,f1.y); av[j].w = pk2(f1.z,f1.w);
        } else {
          av[j] = make_uint4(0u,0u,0u,0u);
        }
      } else {
        av[j] = *(const uint4*)&A[(size_t)(row0+rA)*K + kt*64 + k8];
      }
      bv[j] = *(const uint4*)&Bte[(size_t)rA*K + kt*64 + k8];
    }
    __syncthreads();                   // previous iter's compute done with LDS
    #pragma unroll
    for (int j=0;j<4;++j){
      int cch = t + 256*j;
      int r = cch >> 3;
      int slot = (cch & 7) ^ (r & 7);  // XOR swizzle of 16B slots (bank-conflict fix)
      *(uint4*)&As[r*64 + slot*8] = av[j];
      *(uint4*)&Bs[r*64 + slot*8] = bv[j];
    }
    __syncthreads();
    #pragma unroll
    for (int kk=0;kk<2;++kk){
      bf16x8 af[4], bfr[4];
      const int s = kk*4 + sgrp;
      #pragma unroll
      for (int mi=0;mi<4;++mi){
        int R = wr + mi*16 + lr;
        af[mi] = *(const bf16x8*)&As[R*64 + ((s ^ (R & 7)) << 3)];
      }
      #pragma unroll
      for (int ni=0;ni<4;++ni){
        int Cc = wc + ni*16 + lr;
        bfr[ni] = *(const bf16x8*)&Bs[Cc*64 + ((s ^ (Cc & 7)) << 3)];
      }
      #pragma unroll
      for (int mi=0;mi<4;++mi)
        #pragma unroll
        for (int ni=0;ni<4;++ni)
          acc[mi][ni] = __builtin_amdgcn_mfma_f32_16x16x32_bf16(af[mi], bfr[ni], acc[mi][ni], 0, 0, 0);
    }
  }

  // ---------- epilogue: LDS-staged, full-line row writes ----------
  // D fragment: row=(lane>>4)*4+q (+16*mi), col=lane&15 (+16*ni)
  __syncthreads();                     // done with As/Bs
  if constexpr (FINAL){
    // fp32 scatter: stage 64 rows x 128 cols fp32 (32 KB) per half
    float* stf = (float*)smem;
    #pragma unroll
    for (int h=0; h<2; ++h){
      if ((wid >> 1) == h){
        #pragma unroll
        for (int ni=0;ni<4;++ni){
          const int colg = n0 + wc + ni*16 + lr;
          const float bv_ = bias[(size_t)e*NO + colg];
          #pragma unroll
          for (int mi=0;mi<4;++mi){
            #pragma unroll
            for (int q=0;q<4;++q){
              float v = acc[mi][ni][q] + bv_;
              if (RELU) v = fmaxf(v, 0.f);
              stf[(mi*16 + sgrp*4 + q)*128 + wc + ni*16 + lr] = v;
            }
          }
        }
      }
      __syncthreads();
      // 64 rows x 128 floats; 32 threads/row, float4 each -> 512B contiguous/row
      #pragma unroll
      for (int i=0;i<8;++i){
        int idx = t + 256*i;
        int r = idx >> 5, c4 = idx & 31;
        int atom = sperm[h*64 + r];
        if (atom >= 0)
          *(float4*)&Cf[(size_t)atom*NO + n0 + c4*4] = *(const float4*)&stf[r*128 + c4*4];
      }
      __syncthreads();
    }
  } else {
    // bf16: stage full 128x128 tile (32 KB), write 256B/row contiguous
    unsigned short* st = smem;
    #pragma unroll
    for (int ni=0;ni<4;++ni){
      const int colg = n0 + wc + ni*16 + lr;
      const float bv_ = bias[(size_t)e*NO + colg];
      #pragma unroll
      for (int mi=0;mi<4;++mi){
        #pragma unroll
        for (int q=0;q<4;++q){
          float v = acc[mi][ni][q] + bv_;
          if (RELU) v = fmaxf(v, 0.f);
          st[(wr + mi*16 + sgrp*4 + q)*128 + wc + ni*16 + lr] = f2bf(v);
        }
      }
    }
    __syncthreads();
    #pragma unroll
    for (int i=0;i<8;++i){
      int idx = t + 256*i;
      int r = idx >> 4, c4 = idx & 15;
      *(uint4*)&Cb[(size_t)(row0 + r)*NO + n0 + c4*8] = *(const uint4*)&st[r*128 + c4*8];
    }
  }
}

extern "C" void kernel_launch(void* const* d_in, const int* in_sizes, int n_in,
                              void* d_out, int out_size, void* d_ws, size_t ws_size,
                              hipStream_t stream) {
  const float* X   = (const float*)d_in[0];
  const int*   sym = (const int*)  d_in[1];
  const float* We1 = (const float*)d_in[2];
  const float* be1 = (const float*)d_in[3];
  const float* We2 = (const float*)d_in[4];
  const float* be2 = (const float*)d_in[5];
  const float* Wd1 = (const float*)d_in[6];
  const float* bd1 = (const float*)d_in[7];
  const float* Wd2 = (const float*)d_in[8];
  const float* bd2 = (const float*)d_in[9];
  float* out = (float*)d_out;

  char* ws = (char*)d_ws;
  int* hdr  = (int*)(ws + WS_HDR);
  int* perm = (int*)(ws + WS_PERM);
  unsigned short* W1t = (unsigned short*)(ws + WS_W1T);
  unsigned short* W2t = (unsigned short*)(ws + WS_W2T);
  unsigned short* W3t = (unsigned short*)(ws + WS_W3T);
  unsigned short* W4t = (unsigned short*)(ws + WS_W4T);
  unsigned short* H   = (unsigned short*)(ws + WS_H);
  unsigned short* Z   = (unsigned short*)(ws + WS_Z);
  unsigned short* Dd  = (unsigned short*)(ws + WS_D);   // aliases H (H dead after L2)

  dim3 b256(256);
  route_kernel<<<1, 1024, 0, stream>>>(sym, hdr, perm);
  wconvert<1024, 512><<<dim3( 512/64, 1024/64, NEXP), b256, 0, stream>>>(We1, W1t);
  wconvert< 512, 128><<<dim3( 128/64,  512/64, NEXP), b256, 0, stream>>>(We2, W2t);
  wconvert< 128, 512><<<dim3( 512/64,  128/64, NEXP), b256, 0, stream>>>(Wd1, W3t);
  wconvert< 512,1024><<<dim3(1024/64,  512/64, NEXP), b256, 0, stream>>>(Wd2, W4t);

  // L1: relu(X @ We1 + be1), gather fp32 X rows via perm -> H (bf16)
  gemm_k<1024, 512, true,  true,  false><<<dim3(4, MBLKS), b256, 0, stream>>>(
      nullptr, X, W1t, be1, H, nullptr, hdr, perm);
  // L2: relu(H @ We2 + be2) -> Z
  gemm_k< 512, 128, true,  false, false><<<dim3(1, MBLKS), b256, 0, stream>>>(
      H, nullptr, W2t, be2, Z, nullptr, hdr, perm);
  // L3: relu(Z @ Wd1 + bd1) -> Dd
  gemm_k< 128, 512, true,  false, false><<<dim3(4, MBLKS), b256, 0, stream>>>(
      Z, nullptr, W3t, bd1, Dd, nullptr, hdr, perm);
  // L4: Dd @ Wd2 + bd2, scatter fp32 rows to out via perm
  gemm_k< 512,1024, false, false, true ><<<dim3(8, MBLKS), b256, 0, stream>>>(
      Dd, nullptr, W4t, bd2, nullptr, out, hdr, perm);
}

// Round 3
// 264.822 us; speedup vs baseline: 2.2138x; 2.1534x over previous
//
#include <hip/hip_runtime.h>
#include <hip/hip_bf16.h>
#include <stdint.h>

typedef __bf16 bf16x8 __attribute__((ext_vector_type(8)));
typedef float  f32x4  __attribute__((ext_vector_type(4)));

#define NATOMS  32768
#define NEXP    4
#define MAXROWS (NATOMS + NEXP*128)   // 33280 (max padded rows)
#define MBLKS   (MAXROWS/128)         // 260
#define MGRP    ((MBLKS + 7)/8)       // 33 groups of 8 row-blocks

// ---------------- ws layout (bytes) ----------------
#define WS_HDR   0u
#define WS_PERM  1024u                        // int[33280] -> ends 134144
#define WS_W1T   134144u                      // [4][512][1024] bf16 = 4194304
#define WS_W2T   (WS_W1T + 4194304u)          // [4][128][512]  bf16 = 524288
#define WS_W3T   (WS_W2T + 524288u)           // [4][512][128]  bf16 = 524288
#define WS_W4T   (WS_W3T + 524288u)           // [4][1024][512] bf16 = 4194304
#define WS_H     (WS_W4T + 4194304u)          // [33280][512] bf16 = 34078720
#define WS_Z     (WS_H + 34078720u)           // [33280][128] bf16 = 8519680
#define WS_D     WS_H                         // alias: h dead after L2
#define WS_XB    (WS_Z + 8519680u)            // [32768][1024] bf16 = 67108864
#define WS_TOTAL (WS_XB + 67108864u)          // ~114 MB

__device__ __forceinline__ unsigned short f2bf(float f){
  union { float f; uint32_t u; } v; v.f = f;
  uint32_t r = v.u + 0x7fffu + ((v.u >> 16) & 1u);   // RNE
  return (unsigned short)(r >> 16);
}
__device__ __forceinline__ uint32_t pk2(float a, float b){
  return (uint32_t)f2bf(a) | ((uint32_t)f2bf(b) << 16);
}
__device__ __forceinline__ void glds16(const void* g, void* l){
  __builtin_amdgcn_global_load_lds(
      (const __attribute__((address_space(1))) uint32_t*)g,
      (__attribute__((address_space(3))) uint32_t*)l, 16, 0, 0);
}

// ---------------- routing: stable bucket-by-expert, 128-padded ----------------
__global__ __launch_bounds__(1024) void route_kernel(const int* __restrict__ sym,
                                                     int* __restrict__ hdr,
                                                     int* __restrict__ perm){
  __shared__ unsigned wsumA[16], wsumB[16];
  __shared__ unsigned wexclA[16], wexclB[16];
  __shared__ int pof[NEXP+1];
  __shared__ int tot[NEXP];
  const int t = threadIdx.x;
  const int lane = t & 63, w = t >> 6;
  int c0=0,c1=0,c2=0,c3=0;
  const int base = t*32;                       // 1024*32 == 32768 exactly
  for (int i=0;i<32;++i){
    int s = sym[base+i];
    c0 += (s==0); c1 += (s==1); c2 += (s==2); c3 += (s==3);
  }
  unsigned pA = (unsigned)c0 | ((unsigned)c1<<16);
  unsigned pB = (unsigned)c2 | ((unsigned)c3<<16);
  unsigned iA = pA, iB = pB;
  #pragma unroll
  for (int d=1; d<64; d<<=1){
    unsigned uA = __shfl_up(iA, d, 64);
    unsigned uB = __shfl_up(iB, d, 64);
    if (lane >= d){ iA += uA; iB += uB; }
  }
  unsigned exA = iA - pA, exB = iB - pB;       // in-wave exclusive (packed)
  if (lane == 63){ wsumA[w] = iA; wsumB[w] = iB; }
  __syncthreads();
  if (w == 0 && lane < 16){
    unsigned vA = wsumA[lane], vB = wsumB[lane];
    unsigned jA = vA, jB = vB;
    #pragma unroll
    for (int d=1; d<16; d<<=1){
      unsigned uA = __shfl_up(jA, d, 64);
      unsigned uB = __shfl_up(jB, d, 64);
      if (lane >= d){ jA += uA; jB += uB; }
    }
    wexclA[lane] = jA - vA; wexclB[lane] = jB - vB;
    if (lane == 15){
      tot[0] = (int)(jA & 0xFFFFu); tot[1] = (int)(jA >> 16);
      tot[2] = (int)(jB & 0xFFFFu); tot[3] = (int)(jB >> 16);
      int o = 0; pof[0] = 0;
      for (int e=0;e<NEXP;++e){ o += (tot[e]+127)&~127; pof[e+1]=o; }
      for (int e=0;e<=NEXP;++e) hdr[e]=pof[e];
    }
  }
  __syncthreads();
  const unsigned bA = wexclA[w] + exA, bB = wexclB[w] + exB;
  int p0 = pof[0] + (int)(bA & 0xFFFFu);
  int p1 = pof[1] + (int)(bA >> 16);
  int p2 = pof[2] + (int)(bB & 0xFFFFu);
  int p3 = pof[3] + (int)(bB >> 16);
  const int totpad = pof[NEXP];
  for (int i=t; i<totpad; i+=1024) perm[i] = -1;   // pad rows
  __syncthreads();
  for (int i=0;i<32;++i){
    int a = base+i; int s = sym[a];
    if      (s==0) perm[p0++] = a;
    else if (s==1) perm[p1++] = a;
    else if (s==2) perm[p2++] = a;
    else           perm[p3++] = a;
  }
}

// ---------------- weight convert fp32 [E][K][NO] -> bf16 [E][NO][K] ----------------
template<int K, int NO>
__global__ __launch_bounds__(256) void wconvert(const float* __restrict__ W,
                                                unsigned short* __restrict__ Bt){
  __shared__ unsigned short tile[64][65];
  const int e  = blockIdx.z;
  const int k0 = blockIdx.y * 64;
  const int n0 = blockIdx.x * 64;
  const int t  = threadIdx.x;
  const int c  = t & 63;
  const float* Wb = W + ((size_t)e*K + k0)*NO + n0;
  #pragma unroll
  for (int i=0;i<16;++i){
    int r = (t>>6) + i*4;
    tile[r][c] = f2bf(Wb[(size_t)r*NO + c]);
  }
  __syncthreads();
  unsigned short* Bb = Bt + ((size_t)e*NO + n0)*K + k0;
  #pragma unroll
  for (int i=0;i<16;++i){
    int r = (t>>6) + i*4;
    Bb[(size_t)r*K + c] = tile[c][r];
  }
}

// ---------------- streaming fp32 -> bf16 convert of X (no permutation) ----------------
__global__ __launch_bounds__(256) void xconvert(const float* __restrict__ X,
                                                unsigned short* __restrict__ Xb){
  size_t i = ((size_t)blockIdx.x*256 + threadIdx.x) * 8;
  float4 f0 = *(const float4*)(X+i), f1 = *(const float4*)(X+i+4);
  uint4 o;
  o.x=pk2(f0.x,f0.y); o.y=pk2(f0.z,f0.w); o.z=pk2(f1.x,f1.y); o.w=pk2(f1.z,f1.w);
  *(uint4*)&Xb[i] = o;
}

// ---------------- 128x128 tile MFMA GEMM, m97-style glds staging ----------------
// grid: 1-D, MGRP*8*NT blocks. Decode co-locates all NT n-tiles of a row-block
// on ONE XCD (ids congruent mod 8 within an 8*NT window) -> A-panel fetched
// once per XCD L2 instead of NT times.
// AMODE 0: A = bf16 [Mpad][K], rows row0..row0+127 via glds
// AMODE 1: A = Xb bf16 [NATOMS][K], rows gathered via perm (per-lane glds src)
// AMODE 2: A = Af fp32 [NATOMS][K], reg gather+convert+swizzled ds_write
// LDS staging: linear [128][64]; swizzle baked into per-lane SOURCE chunk
// ((lane&7)^(lane>>3)) so frag reads at chunk s^(R&7) are conflict-free.
template<int K, int NO, int NT, bool RELU, int AMODE, bool FINAL>
__global__ __launch_bounds__(256) void gemm_k(
    const unsigned short* __restrict__ A,
    const float* __restrict__ Af,
    const unsigned short* __restrict__ Bt,
    const float* __restrict__ bias,
    unsigned short* __restrict__ Cb,
    float* __restrict__ Cf,
    const int* __restrict__ hdr,
    const int* __restrict__ perm)
{
  __shared__ __align__(16) unsigned short smem[128*136];  // 34816 B
  __shared__ int sperm[128];
  unsigned short* As = smem;            // [128][64] linear
  unsigned short* Bs = smem + 128*64;   // [128][64] linear

  const int b = blockIdx.x;
  const int grp = b / (8*NT), rem = b % (8*NT);
  const int rowblk = grp*8 + (rem & 7);
  const int row0 = rowblk * 128;
  if (row0 >= hdr[NEXP]) return;
  const int ntile = rem >> 3;
  const int e = (row0 >= hdr[1]) + (row0 >= hdr[2]) + (row0 >= hdr[3]);
  const int n0 = ntile * 128;

  const int t = threadIdx.x;
  const int lane = t & 63, wid = t >> 6;
  if constexpr (FINAL){
    if (t < 128) sperm[t] = perm[row0 + t];
    __syncthreads();
  }

  // ---- staging source pointers (per-lane pre-swizzled chunk) ----
  const int l8 = lane >> 3;                       // row-within-8
  const int scoff = (((lane & 7) ^ l8) << 3);     // swizzled chunk, in shorts
  const unsigned short* asrc[4];
  if constexpr (AMODE == 0){
    #pragma unroll
    for (int i=0;i<4;++i)
      asrc[i] = A + (size_t)(row0 + wid*32 + i*8 + l8)*K + scoff;
  } else if constexpr (AMODE == 1){
    #pragma unroll
    for (int i=0;i<4;++i){
      int atom = perm[row0 + wid*32 + i*8 + l8];
      asrc[i] = A + (size_t)(atom < 0 ? 0 : atom)*K + scoff;  // pad rows: junk, never consumed
    }
  }
  const unsigned short* bsrc[4];
  #pragma unroll
  for (int i=0;i<4;++i)
    bsrc[i] = Bt + ((size_t)e*NO + n0 + wid*32 + i*8 + l8)*K + scoff;

  int patom[4];
  if constexpr (AMODE == 2){
    #pragma unroll
    for (int j=0;j<4;++j) patom[j] = perm[row0 + ((t + 256*j) >> 3)];
  }

  const int lr   = lane & 15;
  const int sgrp = lane >> 4;
  const int wr   = (wid >> 1) * 64;
  const int wc   = (wid & 1) * 64;

  f32x4 acc[4][4];
  const f32x4 z4 = {0.f,0.f,0.f,0.f};
  #pragma unroll
  for (int mi=0;mi<4;++mi)
    #pragma unroll
    for (int ni=0;ni<4;++ni) acc[mi][ni] = z4;

  #pragma unroll 1
  for (int kt = 0; kt < K/64; ++kt){
    uint4 av[4];
    if constexpr (AMODE == 2){
      #pragma unroll
      for (int j=0;j<4;++j){
        int k8 = ((t + 256*j) & 7) * 8;
        if (patom[j] >= 0){
          const float* src = Af + (size_t)patom[j]*K + kt*64 + k8;
          float4 f0 = *(const float4*)src;
          float4 f1 = *(const float4*)(src + 4);
          av[j].x = pk2(f0.x,f0.y); av[j].y = pk2(f0.z,f0.w);
          av[j].z = pk2(f1.x,f1.y); av[j].w = pk2(f1.z,f1.w);
        } else av[j] = make_uint4(0u,0u,0u,0u);
      }
    }
    __syncthreads();                    // previous MFMA done with As/Bs
    if constexpr (AMODE != 2){
      #pragma unroll
      for (int i=0;i<4;++i)
        glds16(asrc[i] + kt*64, As + (wid*4+i)*512);
    } else {
      #pragma unroll
      for (int j=0;j<4;++j){
        int cch = t + 256*j;
        int r = cch >> 3;
        int slot = (cch & 7) ^ (r & 7);
        *(uint4*)&As[r*64 + slot*8] = av[j];
      }
    }
    #pragma unroll
    for (int i=0;i<4;++i)
      glds16(bsrc[i] + kt*64, Bs + (wid*4+i)*512);
    __syncthreads();                    // drains vmcnt (glds) + lgkm (ds_write)

    #pragma unroll
    for (int kk=0;kk<2;++kk){
      bf16x8 af[4], bfr[4];
      const int s = kk*4 + sgrp;
      #pragma unroll
      for (int mi=0;mi<4;++mi){
        int R = wr + mi*16 + lr;
        af[mi] = *(const bf16x8*)&As[R*64 + ((s ^ (R & 7)) << 3)];
      }
      #pragma unroll
      for (int ni=0;ni<4;++ni){
        int Cc = wc + ni*16 + lr;
        bfr[ni] = *(const bf16x8*)&Bs[Cc*64 + ((s ^ (Cc & 7)) << 3)];
      }
      #pragma unroll
      for (int mi=0;mi<4;++mi)
        #pragma unroll
        for (int ni=0;ni<4;++ni)
          acc[mi][ni] = __builtin_amdgcn_mfma_f32_16x16x32_bf16(af[mi], bfr[ni], acc[mi][ni], 0, 0, 0);
    }
  }

  // ---------- epilogue: LDS-staged (padded stride), full-line row writes ----------
  __syncthreads();                      // done with As/Bs
  if constexpr (FINAL){
    float* stf = (float*)smem;          // [64][132] fp32 = 33792 B
    #pragma unroll
    for (int h=0; h<2; ++h){
      if ((wid >> 1) == h){
        #pragma unroll
        for (int ni=0;ni<4;++ni){
          const int colg = n0 + wc + ni*16 + lr;
          const float bv_ = bias[(size_t)e*NO + colg];
          #pragma unroll
          for (int mi=0;mi<4;++mi){
            #pragma unroll
            for (int q=0;q<4;++q){
              float v = acc[mi][ni][q] + bv_;
              if (RELU) v = fmaxf(v, 0.f);
              stf[(mi*16 + sgrp*4 + q)*132 + wc + ni*16 + lr] = v;
            }
          }
        }
      }
      __syncthreads();
      #pragma unroll
      for (int i=0;i<8;++i){
        int idx = t + 256*i;
        int r = idx >> 5, c4 = idx & 31;
        int atom = sperm[h*64 + r];
        if (atom >= 0)
          *(float4*)&Cf[(size_t)atom*NO + n0 + c4*4] = *(const float4*)&stf[r*132 + c4*4];
      }
      __syncthreads();
    }
  } else {
    unsigned short* st = smem;          // [128][136] bf16 = 34816 B
    #pragma unroll
    for (int ni=0;ni<4;++ni){
      const int colg = n0 + wc + ni*16 + lr;
      const float bv_ = bias[(size_t)e*NO + colg];
      #pragma unroll
      for (int mi=0;mi<4;++mi){
        #pragma unroll
        for (int q=0;q<4;++q){
          float v = acc[mi][ni][q] + bv_;
          if (RELU) v = fmaxf(v, 0.f);
          st[(wr + mi*16 + sgrp*4 + q)*136 + wc + ni*16 + lr] = f2bf(v);
        }
      }
    }
    __syncthreads();
    #pragma unroll
    for (int i=0;i<8;++i){
      int idx = t + 256*i;
      int r = idx >> 4, c4 = idx & 15;
      *(uint4*)&Cb[(size_t)(row0 + r)*NO + n0 + c4*8] = *(const uint4*)&st[r*136 + c4*8];
    }
  }
}

extern "C" void kernel_launch(void* const* d_in, const int* in_sizes, int n_in,
                              void* d_out, int out_size, void* d_ws, size_t ws_size,
                              hipStream_t stream) {
  const float* X   = (const float*)d_in[0];
  const int*   sym = (const int*)  d_in[1];
  const float* We1 = (const float*)d_in[2];
  const float* be1 = (const float*)d_in[3];
  const float* We2 = (const float*)d_in[4];
  const float* be2 = (const float*)d_in[5];
  const float* Wd1 = (const float*)d_in[6];
  const float* bd1 = (const float*)d_in[7];
  const float* Wd2 = (const float*)d_in[8];
  const float* bd2 = (const float*)d_in[9];
  float* out = (float*)d_out;

  char* ws = (char*)d_ws;
  int* hdr  = (int*)(ws + WS_HDR);
  int* perm = (int*)(ws + WS_PERM);
  unsigned short* W1t = (unsigned short*)(ws + WS_W1T);
  unsigned short* W2t = (unsigned short*)(ws + WS_W2T);
  unsigned short* W3t = (unsigned short*)(ws + WS_W3T);
  unsigned short* W4t = (unsigned short*)(ws + WS_W4T);
  unsigned short* H   = (unsigned short*)(ws + WS_H);
  unsigned short* Z   = (unsigned short*)(ws + WS_Z);
  unsigned short* Dd  = (unsigned short*)(ws + WS_D);   // aliases H (H dead after L2)
  unsigned short* Xb  = (unsigned short*)(ws + WS_XB);

  const bool big = (ws_size >= (size_t)WS_TOTAL);

  dim3 b256(256);
  route_kernel<<<1, 1024, 0, stream>>>(sym, hdr, perm);
  wconvert<1024, 512><<<dim3( 512/64, 1024/64, NEXP), b256, 0, stream>>>(We1, W1t);
  wconvert< 512, 128><<<dim3( 128/64,  512/64, NEXP), b256, 0, stream>>>(We2, W2t);
  wconvert< 128, 512><<<dim3( 512/64,  128/64, NEXP), b256, 0, stream>>>(Wd1, W3t);
  wconvert< 512,1024><<<dim3(1024/64,  512/64, NEXP), b256, 0, stream>>>(Wd2, W4t);

  // L1: relu(X @ We1 + be1) -> H
  if (big){
    xconvert<<<dim3(NATOMS*1024/8/256), b256, 0, stream>>>(X, Xb);
    gemm_k<1024, 512, 4, true, 1, false><<<dim3(MGRP*8*4), b256, 0, stream>>>(
        Xb, nullptr, W1t, be1, H, nullptr, hdr, perm);
  } else {
    gemm_k<1024, 512, 4, true, 2, false><<<dim3(MGRP*8*4), b256, 0, stream>>>(
        nullptr, X, W1t, be1, H, nullptr, hdr, perm);
  }
  // L2: relu(H @ We2 + be2) -> Z
  gemm_k< 512, 128, 1, true, 0, false><<<dim3(MGRP*8*1), b256, 0, stream>>>(
      H, nullptr, W2t, be2, Z, nullptr, hdr, perm);
  // L3: relu(Z @ Wd1 + bd1) -> Dd
  gemm_k< 128, 512, 4, true, 0, false><<<dim3(MGRP*8*4), b256, 0, stream>>>(
      Z, nullptr, W3t, bd1, Dd, nullptr, hdr, perm);
  // L4: Dd @ Wd2 + bd2, scatter fp32 rows to out via perm
  gemm_k< 512,1024, 8, false, 0, true ><<<dim3(MGRP*8*8), b256, 0, stream>>>(
      Dd, nullptr, W4t, bd2, nullptr, out, hdr, perm);
}